// Round 6
// baseline (118.548 us; speedup 1.0000x reference)
//
#include <hip/hip_runtime.h>
#include <math.h>

// Problem constants (fixed by setup_inputs): B=8, N=2048, C=128, TOP_K=512
// Algebraic structure (verified passing since R1):
//  - adj = softmax(relu(GL GL^T)) + I > 0 everywhere  => att == e, GL unused.
//  - e[b,i,j] = leaky_relu(p_i + q_j) monotone in p_i => keep iff
//    (p_i, -i) >= 512th largest; unselected rows => relu(mean_j h[b,j,:]).
//  - exp(leaky_relu(p+q)) separates at q >= -p; sorted-q order =>
//    suffix/prefix sums per row (boundary lo_i).
//  - p = x@(W@a1), q = x@(W@a2) (R12): no h needed for p,q.
//  - R17 NEW: attention combo is LINEAR in h and h = x@W commutes:
//    out_i = relu( z_i @ W ),  z_i = invD_i*(A_i*SUX_i + B_i*PVX_i) for kept
//    rows (SUX/PVX = scans over x rows in sorted-q order), z_i = mean_j x_j
//    for unkept. h is NEVER materialized; the gemm moves into k_out.
//
// Journal: R9/R11 111.2 -> R13 106.3 (sort||gemm fused) -> R14 138.4 FAILED
// (GEMV in 16 cold blocks; lesson: wide grids for x readers) -> R16 104.8
// (rank kernel replaces bitonic sort; lo/keep via counts).
// Model: harness ws re-poison fill ~42us is INSIDE the timed region; launch
// gaps ~4-6us each; addressable ~62us = gemm 18 + out 10 + scan 6 + pq 3.
// R17: kill the h pipeline via linearity (above). 4 light launches:
//   k_pq (p,q + x col-sum partials) -> k_rank -> k_scan (x-scans + scalar
//   scans) -> k_out (tables + z build + z@W gemm + relu + transposed store).

#define B_ 8
#define N_ 2048
#define C_ 128
#define TOPK_ 512
#define NCH_ 32      // chunks per batch
#define CL_ 64       // chunk length (NCH_*CL_ == N_)
#define NP1_ 2052    // padded N+stride, multiple of 4

// ---------------- ws layout (floats) ----------------
#define P_OFF    ((size_t)0)
#define Q_OFF    (P_OFF + (size_t)B_*N_)
#define LOK_OFF  (Q_OFF + (size_t)B_*N_)            // ints: lo | keep<<16
#define US_OFF   (LOK_OFF + (size_t)B_*N_)          // sorted u = e^q
#define VS_OFF   (US_OFF + (size_t)B_*N_)           // sorted w = e^{.01q}
#define SRT_OFF  (VS_OFF + (size_t)B_*N_)           // ints: source row
#define SUS_OFF  (SRT_OFF + (size_t)B_*N_)          // B*NP1_ scalar suffix(u)
#define PVS_OFF  (SUS_OFF + (size_t)B_*NP1_)        // B*NP1_ scalar prefix(w)
#define SUX_OFF  (PVS_OFF + (size_t)B_*NP1_)        // B*N*128 suffix(u*x)
#define PVX_OFF  (SUX_OFF + (size_t)B_*N_*128)      // B*N*128 eprefix(w*x)
#define TOTU_OFF (PVX_OFF + (size_t)B_*N_*128)      // B*NCH*128
#define TOTV_OFF (TOTU_OFF + (size_t)B_*NCH_*128)
#define XPART_OFF (TOTV_OFF + (size_t)B_*NCH_*128)  // 256*128 x col partials

// ---------------- K0: p = x@(W a1), q = x@(W a2), xpart ---------- (R13-proven)
__global__ __launch_bounds__(256) void k_pq(const float* __restrict__ x,
                                            const float* __restrict__ W,
                                            const float* __restrict__ a,
                                            float* __restrict__ p,
                                            float* __restrict__ q,
                                            float* __restrict__ xpart) {
  __shared__ float al[256];
  __shared__ float wa1[128], wa2[128];
  __shared__ float xps[2][128];
  const int t = threadIdx.x;
  const int r0 = blockIdx.x * 64;
  al[t] = a[t];
  __syncthreads();
  if (t < 128) {
    const float* Wr = W + (size_t)t * 128;
    float s1 = 0.f, s2 = 0.f;
#pragma unroll
    for (int j = 0; j < 128; j += 4) {
      float4 wv = *(const float4*)(Wr + j);
      s1 = fmaf(wv.x, al[j + 0], s1);
      s1 = fmaf(wv.y, al[j + 1], s1);
      s1 = fmaf(wv.z, al[j + 2], s1);
      s1 = fmaf(wv.w, al[j + 3], s1);
      s2 = fmaf(wv.x, al[128 + j + 0], s2);
      s2 = fmaf(wv.y, al[128 + j + 1], s2);
      s2 = fmaf(wv.z, al[128 + j + 2], s2);
      s2 = fmaf(wv.w, al[128 + j + 3], s2);
    }
    wa1[t] = s1; wa2[t] = s2;
  }
  __syncthreads();
  {
    const int row = t >> 2, part = t & 3;   // 4 consecutive lanes per row
    const float* xr = x + (size_t)(r0 + row) * 128 + part * 32;
    const float* w1 = wa1 + part * 32;
    const float* w2 = wa2 + part * 32;
    float sp = 0.f, sq = 0.f;
#pragma unroll
    for (int i = 0; i < 8; ++i) {
      float4 xv = *(const float4*)(xr + 4 * i);
      float4 w1v = *(const float4*)(w1 + 4 * i);
      float4 w2v = *(const float4*)(w2 + 4 * i);
      sp = fmaf(xv.x, w1v.x, sp); sp = fmaf(xv.y, w1v.y, sp);
      sp = fmaf(xv.z, w1v.z, sp); sp = fmaf(xv.w, w1v.w, sp);
      sq = fmaf(xv.x, w2v.x, sq); sq = fmaf(xv.y, w2v.y, sq);
      sq = fmaf(xv.z, w2v.z, sq); sq = fmaf(xv.w, w2v.w, sq);
    }
    sp += __shfl_xor(sp, 1, 64); sp += __shfl_xor(sp, 2, 64);
    sq += __shfl_xor(sq, 1, 64); sq += __shfl_xor(sq, 2, 64);
    if (part == 0) { p[r0 + row] = sp; q[r0 + row] = sq; }
  }
  // x column-sum partials for the unkept-row mean (L1-hot re-read)
  {
    const int cc = t & 127, hh = t >> 7;   // 2 halves x 32 rows
    float s = 0.f;
    for (int r2 = 32 * hh; r2 < 32 * hh + 32; ++r2)
      s += x[(size_t)(r0 + r2) * 128 + cc];
    xps[hh][cc] = s;
  }
  __syncthreads();
  if (t < 128)
    xpart[(size_t)blockIdx.x * 128 + t] = xps[0][t] + xps[1][t];
}

// ---------------- K1: per-row ranks (R16-proven logic, 256 thr) -------------
// Block (b,tile): 64 rows. qrank (scatter u/w/srt), lo = #{q_j < -p_i},
// prank (keep = prank < TOPK). 4 lanes/row, LDS-broadcast compare loops.
__global__ __launch_bounds__(256) void k_rank(const float* __restrict__ q,
                                              const float* __restrict__ p,
                                              float* __restrict__ u_s,
                                              float* __restrict__ v_s,
                                              int* __restrict__ srt,
                                              int* __restrict__ lok) {
  __shared__ float ql[N_], pl[N_];   // 16 KB
  const int blk = blockIdx.x, t = threadIdx.x;
  const int b = blk >> 5, tile = blk & 31;
  const int i0 = tile * 64;
#pragma unroll
  for (int i = 0; i < 2; ++i) {
    ((float4*)ql)[t + 256 * i] = ((const float4*)(q + (size_t)b * N_))[t + 256 * i];
    ((float4*)pl)[t + 256 * i] = ((const float4*)(p + (size_t)b * N_))[t + 256 * i];
  }
  __syncthreads();
  const int row = t >> 2, s = t & 3;
  const int i = i0 + row;
  const float qi = ql[i], pi = pl[i];
  const float negpi = -pi;
  int qr = 0, lo = 0, pr = 0;
  for (int g = s; g < 512; g += 4) {
    float4 qj = ((const float4*)ql)[g];
    float4 pj = ((const float4*)pl)[g];
    const int j0 = 4 * g;
    qr += (qj.x < qi || (qj.x == qi && (j0 + 0) < i)) ? 1 : 0;
    qr += (qj.y < qi || (qj.y == qi && (j0 + 1) < i)) ? 1 : 0;
    qr += (qj.z < qi || (qj.z == qi && (j0 + 2) < i)) ? 1 : 0;
    qr += (qj.w < qi || (qj.w == qi && (j0 + 3) < i)) ? 1 : 0;
    lo += (qj.x < negpi) ? 1 : 0;
    lo += (qj.y < negpi) ? 1 : 0;
    lo += (qj.z < negpi) ? 1 : 0;
    lo += (qj.w < negpi) ? 1 : 0;
    pr += (pj.x > pi || (pj.x == pi && (j0 + 0) < i)) ? 1 : 0;
    pr += (pj.y > pi || (pj.y == pi && (j0 + 1) < i)) ? 1 : 0;
    pr += (pj.z > pi || (pj.z == pi && (j0 + 2) < i)) ? 1 : 0;
    pr += (pj.w > pi || (pj.w == pi && (j0 + 3) < i)) ? 1 : 0;
  }
  qr += __shfl_xor(qr, 1, 64); qr += __shfl_xor(qr, 2, 64);
  lo += __shfl_xor(lo, 1, 64); lo += __shfl_xor(lo, 2, 64);
  pr += __shfl_xor(pr, 1, 64); pr += __shfl_xor(pr, 2, 64);
  if (s == 0) {
    u_s[(size_t)b * N_ + qr] = __expf(qi);
    v_s[(size_t)b * N_ + qr] = __expf(0.01f * qi);
    srt[(size_t)b * N_ + qr] = i;
    lok[(size_t)b * N_ + i] = lo | ((pr < TOPK_) ? 0x10000 : 0);
  }
}

// ---------------- K2: x-scans (blocks 0..255) + scalar scans (256..263) -----
// Chunk block: gather 64 x rows (sorted order) -> chunk-local suffix(u*x),
// exclusive-prefix(w*x) + chunk totals. Scalar blocks: SUS/PVS over u,w.
__global__ __launch_bounds__(256) void k_scan(const float* __restrict__ x,
                                              const float* __restrict__ u_s,
                                              const float* __restrict__ v_s,
                                              const int* __restrict__ srt,
                                              float* __restrict__ SUX,
                                              float* __restrict__ PVX,
                                              float* __restrict__ totU,
                                              float* __restrict__ totV,
                                              float* __restrict__ SUS,
                                              float* __restrict__ PVS) {
  __shared__ float hl[CL_][128];   // 32 KB (chunk blocks: x rows)
  __shared__ float ul[CL_], vl[CL_];
  __shared__ int sl[CL_];
  __shared__ float2 sa[256], sb[256];  // scalar-scan blocks
  const int t = threadIdx.x;
  if (blockIdx.x >= 256) {
    // ---- scalar suffix/prefix scans over sorted u,w (R16-proven) ----
    const int b = blockIdx.x - 256;
    float4 ua = ((const float4*)(u_s + (size_t)b * N_))[2 * t];
    float4 ub = ((const float4*)(u_s + (size_t)b * N_))[2 * t + 1];
    float4 wa = ((const float4*)(v_s + (size_t)b * N_))[2 * t];
    float4 wb = ((const float4*)(v_s + (size_t)b * N_))[2 * t + 1];
    float su = ua.x + ua.y + ua.z + ua.w + ub.x + ub.y + ub.z + ub.w;
    float sw = wa.x + wa.y + wa.z + wa.w + wb.x + wb.y + wb.z + wb.w;
    sa[t] = make_float2(su, sw);
    __syncthreads();
    float2* cur = sa; float2* nxt = sb;
    for (int off = 1; off < 256; off <<= 1) {
      float2 vv = cur[t];
      if (t >= off) { float2 o = cur[t - off]; vv.x += o.x; vv.y += o.y; }
      nxt[t] = vv;
      __syncthreads();
      float2* tmp = cur; cur = nxt; nxt = tmp;
    }
    float2 incl = cur[t];
    float2 tot = cur[255];
    float exclU = incl.x - su, exclW = incl.y - sw;
    float s0 = tot.x - exclU;
    float s1 = s0 - ua.x, s2 = s1 - ua.y, s3 = s2 - ua.z;
    float s4 = s3 - ua.w, s5 = s4 - ub.x, s6 = s5 - ub.y, s7 = s6 - ub.z;
    float p0 = exclW;
    float p1 = p0 + wa.x, p2 = p1 + wa.y, p3 = p2 + wa.z;
    float p4 = p3 + wa.w, p5 = p4 + wb.x, p6 = p5 + wb.y, p7 = p6 + wb.z;
    float* Sb = SUS + (size_t)b * NP1_ + 8 * t;
    float* Pb = PVS + (size_t)b * NP1_ + 8 * t;
    *(float4*)(Sb) = make_float4(s0, s1, s2, s3);
    *(float4*)(Sb + 4) = make_float4(s4, s5, s6, s7);
    *(float4*)(Pb) = make_float4(p0, p1, p2, p3);
    *(float4*)(Pb + 4) = make_float4(p4, p5, p6, p7);
    if (t == 255) {
      SUS[(size_t)b * NP1_ + N_] = 0.f;
      PVS[(size_t)b * NP1_ + N_] = tot.y;
    }
    return;
  }
  // ---- chunk-local scans over x rows (R13-proven structure, h -> x) ----
  const int b = blockIdx.x >> 5, ch = blockIdx.x & 31;
  const int base = b * N_ + ch * CL_;
  if (t < CL_) { ul[t] = u_s[base + t]; vl[t] = v_s[base + t]; sl[t] = srt[base + t]; }
  __syncthreads();
  {
    const int c4 = t & 31, rr = t >> 5;
#pragma unroll
    for (int i = 0; i < 8; ++i) {
      int tt = rr + 8 * i;
      float4 v = *(const float4*)(x + ((size_t)b * N_ + sl[tt]) * 128 + 4 * c4);
      *(float4*)(&hl[tt][4 * c4]) = v;
    }
  }
  __syncthreads();
  if (t < 128) {
    const int c = t;
    float run = 0.f;
    for (int tt = CL_ - 1; tt >= 0; --tt) {
      run = fmaf(ul[tt], hl[tt][c], run);
      SUX[((size_t)(base + tt)) * 128 + c] = run;
    }
    totU[(size_t)(b * NCH_ + ch) * 128 + c] = run;
  } else {
    const int c = t - 128;
    float run2 = 0.f;
    for (int tt = 0; tt < CL_; ++tt) {
      PVX[((size_t)(base + tt)) * 128 + c] = run2;
      run2 = fmaf(vl[tt], hl[tt][c], run2);
    }
    totV[(size_t)(b * NCH_ + ch) * 128 + c] = run2;
  }
}

// ---------------- K3: tables + z build + z@W gemm + relu + store ------------
// Block (b,tile): 64 rows. z_i = invD*(A*SUXc + B*PVXc) (kept) or xm (unkept);
// out rows = relu(z @ W). W staged 64KB LDS; ~132KB total -> 1 block/CU.
__global__ __launch_bounds__(256) void k_out(const float* __restrict__ p,
                                             const int* __restrict__ lok,
                                             const float* __restrict__ SUS,
                                             const float* __restrict__ PVS,
                                             const float* __restrict__ SUX,
                                             const float* __restrict__ PVX,
                                             const float* __restrict__ totU,
                                             const float* __restrict__ totV,
                                             const float* __restrict__ xpart,
                                             const float* __restrict__ W,
                                             float* __restrict__ out) {
  __shared__ float Wl[128 * 128];            // 64 KB
  __shared__ float zl[64 * 132];             // 33.8 KB (pad 132)
  __shared__ union {
    struct { float CSU[(NCH_ + 1) * 128]; float CPV[(NCH_ + 1) * 128]; float xm[128]; } tb;
    float res[64 * 129];                     // 33 KB (post-gemm reuse)
  } u_;
  __shared__ float A_s[64], B_s[64], invD[64];
  __shared__ int lo_s[64], keep_s[64];
  const int b = blockIdx.x >> 5, tile = blockIdx.x & 31;
  const int t = threadIdx.x;
  const int i0 = tile * 64;
  // stage W (L2-hot: same 64KB read by all 256 blocks)
  {
    const float4* W4 = (const float4*)W;
    float4* Wl4 = (float4*)Wl;
#pragma unroll
    for (int i = 0; i < 16; ++i) Wl4[t + 256 * i] = W4[t + 256 * i];
  }
  // cross-chunk tables + x-mean
  if (t < 128) {
    float ms = 0.f;
#pragma unroll
    for (int j = 0; j < 32; ++j) ms += xpart[(size_t)(b * 32 + j) * 128 + t];
    u_.tb.xm[t] = ms * (1.0f / (float)N_);
    float s = 0.f;
    u_.tb.CSU[NCH_ * 128 + t] = 0.f;
    for (int cc = NCH_ - 1; cc >= 0; --cc) {
      s += totU[(size_t)(b * NCH_ + cc) * 128 + t];
      u_.tb.CSU[cc * 128 + t] = s;
    }
  } else {
    const int c2 = t - 128;
    float s2 = 0.f;
    for (int cc = 0; cc < NCH_; ++cc) {
      u_.tb.CPV[cc * 128 + c2] = s2;
      s2 += totV[(size_t)(b * NCH_ + cc) * 128 + c2];
    }
    u_.tb.CPV[NCH_ * 128 + c2] = s2;
  }
  __syncthreads();
  if (t < 64) {  // per-row scalars (lo/keep from rank kernel)
    float pv = p[b * N_ + i0 + t];
    int lk = lok[(size_t)b * N_ + i0 + t];
    keep_s[t] = (lk >> 16) & 1;
    int lo = lk & 0xFFFF;
    lo_s[t] = lo;
    float A = __expf(pv), Bv = __expf(0.01f * pv);
    A_s[t] = A; B_s[t] = Bv;
    float sus = SUS[(size_t)b * NP1_ + lo];
    float pvs = PVS[(size_t)b * NP1_ + lo];
    invD[t] = 1.0f / fmaf(A, sus, Bv * pvs);
  }
  __syncthreads();
  // z build: z_i[c] = invD*(A*SUXc + B*PVXc) or xm[c]
  {
    const int half = t >> 7, c = t & 127;
#pragma unroll 4
    for (int ii2 = 0; ii2 < 64; ii2 += 2) {
      int ii = ii2 + half;
      float zv;
      if (keep_s[ii]) {
        int lo = lo_s[ii];
        float A = A_s[ii], Bv = B_s[ii];
        float suc, pvc;
        if (lo < N_) {
          int chn = lo >> 6;   // / CL_
          size_t ro = ((size_t)(b * N_ + lo)) * 128;
          suc = SUX[ro + c] + u_.tb.CSU[(chn + 1) * 128 + c];
          pvc = PVX[ro + c] + u_.tb.CPV[chn * 128 + c];
        } else {
          suc = 0.f;
          pvc = u_.tb.CPV[NCH_ * 128 + c];
        }
        zv = fmaf(A, suc, Bv * pvc) * invD[ii];
      } else {
        zv = u_.tb.xm[c];
      }
      zl[ii * 132 + c] = zv;
    }
  }
  __syncthreads();
  // gemm: out_rows = z @ W (64x128 @ 128x128), 4x8 per thread (proven shape)
  const int cg = t & 15, rp = t >> 4;
  float acc[4][8];
#pragma unroll
  for (int r = 0; r < 4; ++r)
#pragma unroll
    for (int j = 0; j < 8; ++j) acc[r][j] = 0.f;
  for (int k = 0; k < 128; ++k) {
    const float4* Wr = (const float4*)(Wl + k * 128);
    float4 w0 = Wr[cg];
    float4 w1 = Wr[cg + 16];
#pragma unroll
    for (int r = 0; r < 4; ++r) {
      float zv = zl[(4 * rp + r) * 132 + k];
      acc[r][0] = fmaf(zv, w0.x, acc[r][0]);
      acc[r][1] = fmaf(zv, w0.y, acc[r][1]);
      acc[r][2] = fmaf(zv, w0.z, acc[r][2]);
      acc[r][3] = fmaf(zv, w0.w, acc[r][3]);
      acc[r][4] = fmaf(zv, w1.x, acc[r][4]);
      acc[r][5] = fmaf(zv, w1.y, acc[r][5]);
      acc[r][6] = fmaf(zv, w1.z, acc[r][6]);
      acc[r][7] = fmaf(zv, w1.w, acc[r][7]);
    }
  }
  __syncthreads();   // tables dead; res aliases them
  {
    const int c0 = 4 * cg, c1 = 4 * cg + 64;
#pragma unroll
    for (int r = 0; r < 4; ++r) {
      int row = 4 * rp + r;
#pragma unroll
      for (int j = 0; j < 4; ++j) {
        u_.res[row * 129 + c0 + j] = fmaxf(acc[r][j], 0.f);
        u_.res[row * 129 + c1 + j] = fmaxf(acc[r][4 + j], 0.f);
      }
    }
  }
  __syncthreads();
  // out[b][c][i] = res[i - i0][c]  (proven transposed float4 store)
#pragma unroll
  for (int pass = 0; pass < 8; ++pass) {
    int cc = (t >> 4) + pass * 16;
    int ii4 = (t & 15) * 4;
    float4 v;
    v.x = u_.res[(ii4 + 0) * 129 + cc];
    v.y = u_.res[(ii4 + 1) * 129 + cc];
    v.z = u_.res[(ii4 + 2) * 129 + cc];
    v.w = u_.res[(ii4 + 3) * 129 + cc];
    *(float4*)(out + ((size_t)(b * C_ + cc)) * N_ + i0 + ii4) = v;
  }
}

extern "C" void kernel_launch(void* const* d_in, const int* in_sizes, int n_in,
                              void* d_out, int out_size, void* d_ws, size_t ws_size,
                              hipStream_t stream) {
  (void)in_sizes; (void)n_in; (void)out_size; (void)ws_size;
  const float* x = (const float*)d_in[0];
  const float* W = (const float*)d_in[1];
  const float* a = (const float*)d_in[2];
  // d_in[3] (GL) is provably unused: adj > 0 everywhere.
  float* out = (float*)d_out;
  float* ws = (float*)d_ws;

  float* p    = ws + P_OFF;
  float* q    = ws + Q_OFF;
  int*   lok  = (int*)(ws + LOK_OFF);
  float* u_s  = ws + US_OFF;
  float* v_s  = ws + VS_OFF;
  int*   srt  = (int*)(ws + SRT_OFF);
  float* SUS  = ws + SUS_OFF;
  float* PVS  = ws + PVS_OFF;
  float* SUX  = ws + SUX_OFF;
  float* PVX  = ws + PVX_OFF;
  float* totU = ws + TOTU_OFF;
  float* totV = ws + TOTV_OFF;
  float* xpart = ws + XPART_OFF;

  k_pq<<<dim3((B_ * N_) / 64), dim3(256), 0, stream>>>(x, W, a, p, q, xpart);
  k_rank<<<dim3(B_ * 32), dim3(256), 0, stream>>>(q, p, u_s, v_s, srt, lok);
  k_scan<<<dim3(256 + B_), dim3(256), 0, stream>>>(x, u_s, v_s, srt, SUX, PVX, totU, totV, SUS, PVS);
  k_out<<<dim3(B_ * 32), dim3(256), 0, stream>>>(p, lok, SUS, PVS, SUX, PVX, totU, totV, xpart, W, out);
}